// Round 6
// baseline (417.878 us; speedup 1.0000x reference)
//
#include <hip/hip_runtime.h>
#include <hip/hip_bf16.h>

#define N_NODES 20000
#define E_EDGES 640000
#define DIM 128
#define CAP 96    // Poisson(32) max degree ~65; 96 is >10-sigma safe
#define EPB 64    // edges per block in edge_kernel
#define NPB 8     // nodes per block in node_kernel / flat build
#define XST 264   // padded ushort stride for [64][256] LDS tile

typedef __attribute__((ext_vector_type(8))) short bf16x8;
typedef __attribute__((ext_vector_type(4))) float f32x4;
typedef __attribute__((ext_vector_type(4))) unsigned u32x4;

#define LOG2E 1.44269504f
__device__ __forceinline__ float fsilu(float x) {
    return x * __builtin_amdgcn_rcpf(1.f + __builtin_amdgcn_exp2f(-LOG2E * x));
}
__device__ __forceinline__ float fsig(float x) {
    return __builtin_amdgcn_rcpf(1.f + __builtin_amdgcn_exp2f(-LOG2E * x));
}

__device__ __forceinline__ unsigned short f2bf(float x) {
    union { float f; unsigned u; } v; v.f = x;
    unsigned r = (v.u + 0x7fffu + ((v.u >> 16) & 1u)) >> 16;
    return (unsigned short)r;
}
__device__ __forceinline__ float bf2f(unsigned short s) {
    union { unsigned u; float f; } v; v.u = ((unsigned)s) << 16;
    return v.f;
}
// pack two floats to packed bf16 {lo,hi} with round-half-up
__device__ __forceinline__ unsigned pack_bf16(float lo, float hi) {
    union { float f; unsigned u; } a, b; a.f = lo; b.f = hi;
    unsigned ul = a.u + 0x8000u, uh = b.u + 0x8000u;
    return __builtin_amdgcn_perm(uh, ul, 0x07060302u);
}

// ------- fused pre-kernel: weight prep (64) + lin (625) + adj build (2500) -------
#define PRE_PREP_BLOCKS 64
#define PRE_LIN_BLOCKS  625   // 32 nodes per block
#define PRE_ADJ_BLOCKS  2500
__global__ __launch_bounds__(256) void pre_kernel(
    const float* __restrict__ w1, const float* __restrict__ w2,
    unsigned short* __restrict__ w1b, float* __restrict__ w1p,
    unsigned short* __restrict__ w2b,
    const float* __restrict__ h, const float* __restrict__ lw,
    const float* __restrict__ lb, float* __restrict__ x,
    unsigned short* __restrict__ xb,
    const int* __restrict__ edges,
    const float* __restrict__ dist, const float* __restrict__ emask,
    int* __restrict__ cnt,
    int* __restrict__ adjc, float2* __restrict__ dm, int E) {
    __shared__ float hs[32][128];
    int b = blockIdx.x;
    int t = threadIdx.x;

    if (b < PRE_PREP_BLOCKS) {
        int i = b * 256 + t;
        const int stride = PRE_PREP_BLOCKS * 256;
        for (int idx = i; idx < 256 * 256; idx += stride) {
            int o = idx >> 8, k = idx & 255;
            w1b[idx] = f2bf(w1[o * 257 + k]);
        }
        // w2b k-order permuted: within each 32-chunk b2: pos b2+2l <- k=b2+l ; b2+2l+1 <- k=b2+16+l
        for (int idx = i; idx < 128 * 256; idx += stride) {
            int n2 = idx >> 8, p = idx & 255;
            int bb = p & ~31, off = p & 31;
            int ksrc = bb + (off >> 1) + ((off & 1) << 4);
            w2b[idx] = f2bf(w2[n2 * 256 + ksrc]);
        }
        // w1last in the SAME permuted order as the a1 LDS tile / w2b k-order
        for (int idx = i; idx < 256; idx += stride) {
            int bb = idx & ~31, off = idx & 31;
            int ksrc = bb + (off >> 1) + ((off & 1) << 4);
            w1p[idx] = w1[ksrc * 257 + 256];
        }
    } else if (b < PRE_PREP_BLOCKS + PRE_LIN_BLOCKS) {
        int nb = b - PRE_PREP_BLOCKS;
        int n0 = nb * 32;
        int ch = t & 127, g = t >> 7;   // g in {0,1}, 16 nodes each
#pragma unroll
        for (int j = 0; j < 16; ++j) hs[g * 16 + j][ch] = h[(size_t)(n0 + g * 16 + j) * DIM + ch];
        __syncthreads();
        float acc[16];
#pragma unroll
        for (int j = 0; j < 16; ++j) acc[j] = 0.f;
        for (int kc = 0; kc < 128; kc += 4) {
            float4 wv = *(const float4*)&lw[(size_t)ch * DIM + kc];
#pragma unroll
            for (int j = 0; j < 16; ++j) {
                float4 hv = *(const float4*)&hs[g * 16 + j][kc];
                acc[j] += wv.x * hv.x + wv.y * hv.y + wv.z * hv.z + wv.w * hv.w;
            }
        }
        float bias = lb[ch];
#pragma unroll
        for (int j = 0; j < 16; ++j) {
            float v = acc[j] + bias;
            int n = n0 + g * 16 + j;
            x[(size_t)n * DIM + ch] = v;
            xb[(size_t)n * DIM + ch] = f2bf(v);
        }
    } else {
        int e = (b - PRE_PREP_BLOCKS - PRE_LIN_BLOCKS) * 256 + t;
        if (e < E) {
            int r = edges[e];
            int col = edges[E + e];
            float em = emask[e];          // coalesced here (sequential e)
            float dv = dist[e] * em;
            int slot = atomicAdd(&cnt[r], 1);
            if (slot < CAP) {
                adjc[(size_t)r * CAP + slot] = col;
                float2 de; de.x = dv; de.y = em;
                dm[(size_t)r * CAP + slot] = de;
            }
        }
    }
}

// ------- scan_kernel: exclusive prefix sum of clamped cnt -> off[N+1] -------
__global__ __launch_bounds__(1024) void scan_kernel(const int* __restrict__ cnt,
                                                    int* __restrict__ off) {
    __shared__ int wsum[16], wbase[16];
    int t = threadIdx.x;
    int lane = t & 63, wid = t >> 6;
    int base = t * 20;
    int loc[20];
    int s = 0;
#pragma unroll
    for (int i = 0; i < 20; ++i) {
        int idx = base + i;
        int v = 0;
        if (idx < N_NODES) { v = cnt[idx]; v = v > CAP ? CAP : v; }
        loc[i] = s; s += v;
    }
    int inc = s;
#pragma unroll
    for (int d = 1; d < 64; d <<= 1) {
        int u = __shfl_up(inc, d);
        if (lane >= d) inc += u;
    }
    if (lane == 63) wsum[wid] = inc;
    __syncthreads();
    if (t < 16) {
        int v = wsum[t];
        int inc2 = v;
#pragma unroll
        for (int d = 1; d < 16; d <<= 1) {
            int u = __shfl_up(inc2, d);
            if (t >= d) inc2 += u;
        }
        wbase[t] = inc2 - v;
        if (t == 15) off[N_NODES] = inc2;
    }
    __syncthreads();
    int ex = wbase[wid] + inc - s;
#pragma unroll
    for (int i = 0; i < 20; ++i) {
        int idx = base + i;
        if (idx < N_NODES) off[idx] = ex + loc[i];
    }
}

// ------- mid_kernel: prc (1250 blocks) + flat edge-list build (2500 blocks) -------
#define MID_PRC_BLOCKS 1250    // N/16
#define MID_FLAT_BLOCKS 2500   // N/8
__global__ __launch_bounds__(256) void mid_kernel(
    const unsigned short* __restrict__ xb,
    const unsigned short* __restrict__ w1b,
    const float* __restrict__ b1,
    unsigned short* __restrict__ prb, unsigned short* __restrict__ pcb,
    const int* __restrict__ adjc, const float2* __restrict__ dm,
    const int* __restrict__ cnt, const int* __restrict__ off,
    int4* __restrict__ flat) {
    int b = blockIdx.x;
    if (b < MID_PRC_BLOCKS) {
        int n0 = b * 16;
        int w = threadIdx.x >> 6, lane = threadIdx.x & 63;
        int lrow = lane & 15, quad = lane >> 4;

        bf16x8 a[4];
#pragma unroll
        for (int kk = 0; kk < 4; ++kk)
            a[kk] = *(const bf16x8*)&xb[(size_t)(n0 + lrow) * DIM + kk * 32 + quad * 8];

        f32x4 z = {0.f, 0.f, 0.f, 0.f};
#pragma unroll
        for (int i = 0; i < 8; ++i) {
            int gt = w * 8 + i;
            int half = gt >> 4;            // 0 -> prb, 1 -> pcb
            int obase = (gt & 15) * 16;
            f32x4 acc = z;
#pragma unroll
            for (int kk = 0; kk < 4; ++kk) {
                bf16x8 bfrag = *(const bf16x8*)&w1b[(size_t)(obase + lrow) * 256 + half * 128 + kk * 32 + quad * 8];
                acc = __builtin_amdgcn_mfma_f32_16x16x32_bf16(a[kk], bfrag, acc, 0, 0, 0);
            }
            int o = obase + lrow;
            if (half == 0) {
                float bias = b1[o];
#pragma unroll
                for (int r = 0; r < 4; ++r)
                    prb[(size_t)(n0 + quad * 4 + r) * 256 + o] = f2bf(acc[r] + bias);
            } else {
#pragma unroll
                for (int r = 0; r < 4; ++r)
                    pcb[(size_t)(n0 + quad * 4 + r) * 256 + o] = f2bf(acc[r]);
            }
        }
    } else {
        int fb = b - MID_PRC_BLOCKS;
        int n0 = fb * NPB;
        int jg = threadIdx.x >> 5, l = threadIdx.x & 31;
        int n = n0 + jg;
        int c = cnt[n]; c = c > CAP ? CAP : c;
        int o = off[n];
        const int* al = adjc + (size_t)n * CAP;
        const float2* dl = dm + (size_t)n * CAP;
        for (int i = l; i < c; i += 32) {
            float2 de = dl[i];
            int4 wv;
            union { float f; int i; } u1, u2; u1.f = de.x; u2.f = de.y;
            wv.x = n; wv.y = al[i]; wv.z = u1.i; wv.w = u2.i;
            flat[o + i] = wv;
        }
    }
}

// ---------------- Kernel 4: edge MLP over flat adj-ordered list ----------------
// Each thread reads its own flat[] entry (8-lane broadcast) and issues its 8
// prb/pcb gather loads BEFORE any barrier -- the first __syncthreads only
// protects the w1ps stage and overlaps the load latency.
__global__ __launch_bounds__(512, 4) void edge_kernel(
    const unsigned short* __restrict__ prb, const unsigned short* __restrict__ pcb,
    const int4* __restrict__ flat, const int* __restrict__ off,
    const float* __restrict__ w1p,
    const unsigned short* __restrict__ w2b, const float* __restrict__ b2,
    const float* __restrict__ w3, const float* __restrict__ b3v,
    float* __restrict__ attv) {
    __shared__ unsigned short buf[EPB * XST];
    __shared__ float part[8][EPB];
    __shared__ float w1ps[256];

    int tid = threadIdx.x;
    int eb = blockIdx.x * EPB;
    int count = off[N_NODES];

    if (tid < 256) w1ps[tid] = w1p[tid];

    // ---- per-thread flat read + gather load issue (pre-barrier)
    int ge = tid >> 3, cb = tid & 7;
    int eidx = eb + ge;
    int4 fv;
    if (eidx < count) fv = flat[eidx];
    else { fv.x = 0; fv.y = 0; fv.z = 0; fv.w = 0; }
    const unsigned short* prow = prb + (size_t)fv.x * 256 + cb * 32;
    const unsigned short* pcp  = pcb + (size_t)fv.y * 256 + cb * 32;
    union { int i; float f; } ud; ud.i = fv.z;
    float d = ud.f;

    bf16x8 pA0 = *(const bf16x8*)&prow[0];
    bf16x8 pB0 = *(const bf16x8*)&prow[16];
    bf16x8 qA0 = *(const bf16x8*)&pcp[0];
    bf16x8 qB0 = *(const bf16x8*)&pcp[16];
    bf16x8 pA1 = *(const bf16x8*)&prow[8];
    bf16x8 pB1 = *(const bf16x8*)&prow[24];
    bf16x8 qA1 = *(const bf16x8*)&pcp[8];
    bf16x8 qB1 = *(const bf16x8*)&pcp[24];

    int wave = tid >> 6, lane = tid & 63;
    int lrow = lane & 15, quad = lane >> 4;
    int n2 = wave * 16 + lrow;
    float bias2 = b2[n2];
    float w3v = w3[n2];

    __syncthreads();   // w1ps ready (loads drain here too)

    // ---- layer-1 epilogue: pairs (o, o+16) pack to the permuted position
    // matching w2b's k-order. 16 words then 4x ds_write_b128.
    {
        const float* wp = &w1ps[cb * 32];
        unsigned u[16];
#pragma unroll
        for (int l = 0; l < 8; ++l) {
            float s0 = bf2f((unsigned short)pA0[l]) + bf2f((unsigned short)qA0[l]) + d * wp[2 * l];
            float s1 = bf2f((unsigned short)pB0[l]) + bf2f((unsigned short)qB0[l]) + d * wp[2 * l + 1];
            u[l] = pack_bf16(fsilu(s0), fsilu(s1));
        }
#pragma unroll
        for (int l = 0; l < 8; ++l) {
            float s0 = bf2f((unsigned short)pA1[l]) + bf2f((unsigned short)qA1[l]) + d * wp[16 + 2 * l];
            float s1 = bf2f((unsigned short)pB1[l]) + bf2f((unsigned short)qB1[l]) + d * wp[16 + 2 * l + 1];
            u[8 + l] = pack_bf16(fsilu(s0), fsilu(s1));
        }
        u32x4* w4 = (u32x4*)&buf[ge * XST + cb * 32];
        u32x4 v0 = {u[0], u[1], u[2], u[3]};
        u32x4 v1 = {u[4], u[5], u[6], u[7]};
        u32x4 v2 = {u[8], u[9], u[10], u[11]};
        u32x4 v3 = {u[12], u[13], u[14], u[15]};
        w4[0] = v0; w4[1] = v1; w4[2] = v2; w4[3] = v3;
    }
    __syncthreads();

    // ---- layer 2: wave covers 16 of 128 N2 (k-order permuted on both sides)
    f32x4 zz = {0.f, 0.f, 0.f, 0.f};
    f32x4 acc2[4];
#pragma unroll
    for (int mt = 0; mt < 4; ++mt) acc2[mt] = zz;

    for (int kk = 0; kk < 8; ++kk) {
        int ka = kk * 32 + quad * 8;
        bf16x8 bfrag = *(const bf16x8*)&w2b[(size_t)n2 * 256 + ka];
#pragma unroll
        for (int mt = 0; mt < 4; ++mt) {
            bf16x8 a = *(bf16x8*)&buf[(mt * 16 + lrow) * XST + ka];
            acc2[mt] = __builtin_amdgcn_mfma_f32_16x16x32_bf16(a, bfrag, acc2[mt], 0, 0, 0);
        }
    }

    // ---- layer 3 in registers
    float s[4][4];
#pragma unroll
    for (int mt = 0; mt < 4; ++mt)
#pragma unroll
        for (int r = 0; r < 4; ++r)
            s[mt][r] = fsilu(acc2[mt][r] + bias2) * w3v;
#pragma unroll
    for (int off2 = 1; off2 < 16; off2 <<= 1) {
#pragma unroll
        for (int mt = 0; mt < 4; ++mt)
#pragma unroll
            for (int r = 0; r < 4; ++r)
                s[mt][r] += __shfl_xor(s[mt][r], off2);
    }
    if (lrow == 0) {
#pragma unroll
        for (int mt = 0; mt < 4; ++mt)
#pragma unroll
            for (int r = 0; r < 4; ++r)
                part[wave][mt * 16 + quad * 4 + r] = s[mt][r];
    }
    __syncthreads();

    if (tid < EPB) {
        int idx = eb + tid;
        if (idx < count) {
            float ssum = b3v[0];
#pragma unroll
            for (int w = 0; w < 8; ++w) ssum += part[w][tid];
            union { int i; float f; } ue; ue.i = flat[idx].w;
            attv[idx] = fsig(ssum) * ue.f;
        }
    }
}

// ---------------- Kernel 5: aggregate + node MLP + LNs ----------------
// Gather re-laned: lane = (edge-slot i 0..3, channel-oct co 0..15); one
// dwordx4 per edge-slot per iter (was 4 scalar dwords); 2 iterations in
// flight; 2-stage shfl_xor(16,32) combines the 4 edge slots.
__global__ __launch_bounds__(256) void node_kernel(
    const float* __restrict__ attv, const int* __restrict__ adjc,
    const int* __restrict__ cnt, const int* __restrict__ off,
    const unsigned short* __restrict__ xb,
    const float* __restrict__ x,
    const float* __restrict__ w1, const float* __restrict__ bb1,
    const float* __restrict__ lng, const float* __restrict__ lnb,
    const float* __restrict__ w2, const float* __restrict__ bb2,
    const float* __restrict__ gF, const float* __restrict__ bF,
    float* __restrict__ out, int E) {
    __shared__ float atts[NPB][CAP];
    __shared__ int   cols[NPB][CAP];
    __shared__ float outv[NPB][128];
    __shared__ float bufs[NPB][128];
    __shared__ float mu_s[NPB], rs_s[NPB];
    __shared__ int cnts[NPB];

    int t = threadIdx.x;
    int n0 = blockIdx.x * NPB;

    if (t < NPB) { int c = cnt[n0 + t]; cnts[t] = c > CAP ? CAP : c; }
    __syncthreads();

    {
        int jg = t >> 5, l = t & 31;
        int c = cnts[jg];
        const int* al = adjc + (size_t)(n0 + jg) * CAP;
        const float* av = attv + off[n0 + jg];
        for (int i = l; i < c; i += 32) {
            atts[jg][i] = av[i];
            cols[jg][i] = al[i];
        }
    }
    __syncthreads();

    int w = t >> 6, lane = t & 63;
    int islot = lane >> 4;      // edge slot 0..3
    int co = lane & 15;         // channel oct
#pragma unroll
    for (int jj = 0; jj < 2; ++jj) {
        int j = w * 2 + jj;
        int c = cnts[j];
        float acc[8];
#pragma unroll
        for (int k = 0; k < 8; ++k) acc[k] = 0.f;
        for (int base = 0; base < c; base += 8) {
            int i0 = base + islot, i1 = base + 4 + islot;
            bool k0 = i0 < c, k1 = i1 < c;
            int c0 = cols[j][k0 ? i0 : 0];
            int c1 = cols[j][k1 ? i1 : 0];
            float a0 = k0 ? atts[j][i0] : 0.f;
            float a1 = k1 ? atts[j][i1] : 0.f;
            bf16x8 q0 = *(const bf16x8*)&xb[(size_t)c0 * DIM + co * 8];
            bf16x8 q1 = *(const bf16x8*)&xb[(size_t)c1 * DIM + co * 8];
#pragma unroll
            for (int k = 0; k < 8; ++k) acc[k] += a0 * bf2f((unsigned short)q0[k]);
#pragma unroll
            for (int k = 0; k < 8; ++k) acc[k] += a1 * bf2f((unsigned short)q1[k]);
        }
#pragma unroll
        for (int k = 0; k < 8; ++k) {
            acc[k] += __shfl_xor(acc[k], 16);
            acc[k] += __shfl_xor(acc[k], 32);
        }
        if (islot == 0) {
            float4 v0 = {acc[0] * 0.01f, acc[1] * 0.01f, acc[2] * 0.01f, acc[3] * 0.01f};
            float4 v1 = {acc[4] * 0.01f, acc[5] * 0.01f, acc[6] * 0.01f, acc[7] * 0.01f};
            *(float4*)&outv[j][co * 8] = v0;
            *(float4*)&outv[j][co * 8 + 4] = v1;
        }
    }
    __syncthreads();

    int h = t >> 7, ch = t & 127;
    float xres[4];
#pragma unroll
    for (int jj = 0; jj < 4; ++jj)
        xres[jj] = x[(size_t)(n0 + h * 4 + jj) * DIM + ch];

    float a1[4] = {0, 0, 0, 0};
    for (int kc = 0; kc < 128; kc += 4) {
        float4 wv = *(const float4*)&w1[(size_t)ch * DIM + kc];
#pragma unroll
        for (int jj = 0; jj < 4; ++jj) {
            int j = h * 4 + jj;
            float4 ov = *(const float4*)&outv[j][kc];
            a1[jj] += wv.x * ov.x + wv.y * ov.y + wv.z * ov.z + wv.w * ov.w;
        }
    }
    float bias1 = bb1[ch];
#pragma unroll
    for (int jj = 0; jj < 4; ++jj) bufs[h * 4 + jj][ch] = a1[jj] + bias1;
    __syncthreads();

    {
        int j = t >> 5, l = t & 31;
        float s = 0.f, qq = 0.f;
#pragma unroll
        for (int i = 0; i < 4; ++i) { float v = bufs[j][l + 32 * i]; s += v; qq += v * v; }
#pragma unroll
        for (int off2 = 16; off2; off2 >>= 1) { s += __shfl_xor(s, off2); qq += __shfl_xor(qq, off2); }
        if (l == 0) {
            float mu = s * (1.f / 128.f);
            float var = qq * (1.f / 128.f) - mu * mu;
            mu_s[j] = mu; rs_s[j] = __builtin_amdgcn_rsqf(var + 1e-5f);
        }
    }
    __syncthreads();

    float g = lng[ch], bb = lnb[ch];
    float h2[4];
#pragma unroll
    for (int jj = 0; jj < 4; ++jj) {
        int j = h * 4 + jj;
        h2[jj] = fsilu((bufs[j][ch] - mu_s[j]) * rs_s[j] * g + bb);
    }
    __syncthreads();
#pragma unroll
    for (int jj = 0; jj < 4; ++jj) bufs[h * 4 + jj][ch] = h2[jj];
    __syncthreads();

    float a3[4] = {0, 0, 0, 0};
    for (int kc = 0; kc < 128; kc += 4) {
        float4 wv = *(const float4*)&w2[(size_t)ch * DIM + kc];
#pragma unroll
        for (int jj = 0; jj < 4; ++jj) {
            int j = h * 4 + jj;
            float4 bv = *(const float4*)&bufs[j][kc];
            a3[jj] += wv.x * bv.x + wv.y * bv.y + wv.z * bv.z + wv.w * bv.w;
        }
    }
    float bias2 = bb2[ch];
    float hh[4];
#pragma unroll
    for (int jj = 0; jj < 4; ++jj) hh[jj] = a3[jj] + bias2 + xres[jj];
    __syncthreads();
#pragma unroll
    for (int jj = 0; jj < 4; ++jj) bufs[h * 4 + jj][ch] = hh[jj];
    __syncthreads();

    {
        int j = t >> 5, l = t & 31;
        float s = 0.f, qq = 0.f;
#pragma unroll
        for (int i = 0; i < 4; ++i) { float v = bufs[j][l + 32 * i]; s += v; qq += v * v; }
#pragma unroll
        for (int off2 = 16; off2; off2 >>= 1) { s += __shfl_xor(s, off2); qq += __shfl_xor(qq, off2); }
        if (l == 0) {
            float mu = s * (1.f / 128.f);
            float var = qq * (1.f / 128.f) - mu * mu;
            mu_s[j] = mu; rs_s[j] = __builtin_amdgcn_rsqf(var + 1e-5f);
        }
    }
    __syncthreads();

    float gf = gF[ch], bf = bF[ch];
#pragma unroll
    for (int jj = 0; jj < 4; ++jj) {
        int j = h * 4 + jj;
        float y = (hh[jj] - mu_s[j]) * rs_s[j] * gf + bf;
        out[(size_t)(n0 + j) * DIM + ch] = fsilu(y);
    }
}

extern "C" void kernel_launch(void* const* d_in, const int* in_sizes, int n_in,
                              void* d_out, int out_size, void* d_ws, size_t ws_size,
                              hipStream_t stream) {
    const float* h         = (const float*)d_in[0];
    const float* distances = (const float*)d_in[1];
    const float* edge_mask = (const float*)d_in[3];
    const float* lin_w     = (const float*)d_in[4];
    const float* lin_b     = (const float*)d_in[5];
    const float* att_w1    = (const float*)d_in[6];
    const float* att_b1    = (const float*)d_in[7];
    const float* att_w2    = (const float*)d_in[8];
    const float* att_b2    = (const float*)d_in[9];
    const float* att_w3    = (const float*)d_in[10];
    const float* att_b3    = (const float*)d_in[11];
    const float* nm_w1     = (const float*)d_in[12];
    const float* nm_b1     = (const float*)d_in[13];
    const float* nm_ln_g   = (const float*)d_in[14];
    const float* nm_ln_b   = (const float*)d_in[15];
    const float* nm_w2     = (const float*)d_in[16];
    const float* nm_b2     = (const float*)d_in[17];
    const float* ln_g      = (const float*)d_in[18];
    const float* ln_b      = (const float*)d_in[19];
    const int*   edges     = (const int*)d_in[20];
    float* out = (float*)d_out;

    const int N = N_NODES, E = E_EDGES;

    char* ws = (char*)d_ws;
    float* x            = (float*)ws;            ws += (size_t)N * DIM * 4;
    unsigned short* xb  = (unsigned short*)ws;   ws += (size_t)N * DIM * 2;
    int* cnt            = (int*)ws;              ws += (size_t)N * 4;
    int* off            = (int*)ws;              ws += (size_t)(N + 4) * 4;
    int* adjc           = (int*)ws;              ws += (size_t)N * CAP * 4;
    float2* dm          = (float2*)ws;           ws += (size_t)N * CAP * 8;
    float* attv         = (float*)ws;            ws += (size_t)E * 4;
    unsigned short* w1b = (unsigned short*)ws;   ws += 256 * 256 * 2;
    float* w1p          = (float*)ws;            ws += 256 * 4;
    unsigned short* w2b = (unsigned short*)ws;   ws += 128 * 256 * 2;
    unsigned short* prb = (unsigned short*)ws;   ws += (size_t)N * 256 * 2;
    unsigned short* pcb = (unsigned short*)ws;   ws += (size_t)N * 256 * 2;
    int4* flat          = (int4*)ws;             ws += (size_t)E * 16;

    hipMemsetAsync(cnt, 0, (size_t)N * 4, stream);

    pre_kernel<<<PRE_PREP_BLOCKS + PRE_LIN_BLOCKS + PRE_ADJ_BLOCKS, 256, 0, stream>>>(
        att_w1, att_w2, w1b, w1p, w2b,
        h, lin_w, lin_b, x, xb,
        edges, distances, edge_mask, cnt, adjc, dm, E);
    scan_kernel<<<1, 1024, 0, stream>>>(cnt, off);
    mid_kernel<<<MID_PRC_BLOCKS + MID_FLAT_BLOCKS, 256, 0, stream>>>(
        xb, w1b, att_b1, prb, pcb, adjc, dm, cnt, off, flat);
    edge_kernel<<<E / EPB, 512, 0, stream>>>(prb, pcb, flat, off,
                                             w1p, w2b, att_b2,
                                             att_w3, att_b3, attv);
    node_kernel<<<N / NPB, 256, 0, stream>>>(attv, adjc, cnt, off, xb, x,
                                             nm_w1, nm_b1, nm_ln_g, nm_ln_b,
                                             nm_w2, nm_b2, ln_g, ln_b, out, E);
}